// Round 1
// baseline (360.173 us; speedup 1.0000x reference)
//
#include <hip/hip_runtime.h>
#include <math.h>

#define Bn 8
#define Qn 20
#define Pn 12
#define Nn 4096
#define Gn 2048
#define Mn 1280   /* Q*FACTOR */
#define Fn 64
#define KNB 7     /* K_NEIGHBORS - 1 */

// ---------------- workspace layout (float units) ----------------
// cham : [0,      1920)   (B,Q,P)
// ns   : [1920,   3840)
// dd   : [3840,   5760)
// cost : [5760,   7680)
// cnt  : [7680,   7776)   (B,P)
// rows : [7776,   7872)   int (B,P)
// acc  : [7872,   7888)   scalars: 0 cls, 1 param, 2 pvd, 3 rep, 4 ch1, 5 ch2

__global__ void zero_acc_kernel(float* acc) {
    if (threadIdx.x < 16) acc[threadIdx.x] = 0.f;
}

// One block per (b,q); computes cham_raw, normal_sim, dist_diff, cost for all p,
// plus mask counts (written once by the q==0 block).
__global__ void cost_kernel(const float* __restrict__ pred_normals,
                            const float* __restrict__ pred_distances,
                            const float* __restrict__ gt_normals,
                            const float* __restrict__ gt_distances,
                            const float* __restrict__ points,
                            const int*   __restrict__ gt_masks,
                            float* __restrict__ cham, float* __restrict__ ns,
                            float* __restrict__ dd, float* __restrict__ cost,
                            float* __restrict__ cnt) {
    const int bq = blockIdx.x;
    const int b = bq / Qn, q = bq % Qn;
    const int tid = threadIdx.x;

    const float nx = pred_normals[(b * Qn + q) * 3 + 0];
    const float ny = pred_normals[(b * Qn + q) * 3 + 1];
    const float nz = pred_normals[(b * Qn + q) * 3 + 2];
    const float dq = pred_distances[b * Qn + q];

    float accs[Pn], accw[Pn];
#pragma unroll
    for (int p = 0; p < Pn; ++p) { accs[p] = 0.f; accw[p] = 0.f; }

    const float* ptb = points + (size_t)b * Nn * 3;
    const int*   mb  = gt_masks + (size_t)b * Pn * Nn;

    for (int n = tid; n < Nn; n += 256) {
        float px = ptb[n * 3 + 0], py = ptb[n * 3 + 1], pz = ptb[n * 3 + 2];
        float pp = fabsf(px * nx + py * ny + pz * nz - dq);
#pragma unroll
        for (int p = 0; p < Pn; ++p) {
            float m = (float)mb[(size_t)p * Nn + n];
            accs[p] += pp * m;
            accw[p] += m;
        }
    }

    __shared__ float s[2 * Pn][256];
#pragma unroll
    for (int p = 0; p < Pn; ++p) { s[p][tid] = accs[p]; s[p + Pn][tid] = accw[p]; }
    __syncthreads();
    for (int off = 128; off > 0; off >>= 1) {
        if (tid < off) {
#pragma unroll
            for (int r = 0; r < 2 * Pn; ++r) s[r][tid] += s[r][tid + off];
        }
        __syncthreads();
    }

    if (tid < Pn) {
        const int p = tid;
        float c  = s[p + Pn][0];
        float cv = s[p][0] / fmaxf(c, 1.f);
        float gnx = gt_normals[(b * Pn + p) * 3 + 0];
        float gny = gt_normals[(b * Pn + p) * 3 + 1];
        float gnz = gt_normals[(b * Pn + p) * 3 + 2];
        float nsim = 1.f - fabsf(nx * gnx + ny * gny + nz * gnz);
        float ddv  = fabsf(dq - gt_distances[b * Pn + p]);
        int idx = (b * Qn + q) * Pn + p;
        cham[idx] = cv;
        ns[idx]   = nsim;
        dd[idx]   = ddv;
        cost[idx] = nsim + 0.5f * ddv + 5.f * ((c > 0.f) ? cv : 1.f);
        if (q == 0) cnt[b * Pn + p] = c;
    }
}

// Wave-parallel Jonker-Volgenant (e-maxx) per batch. One block = one wave = one batch.
// Lane j owns column j. float64 throughout, pad cost 1e6 — exact reference semantics.
__global__ void hungarian_kernel(const float* __restrict__ cost, int* __restrict__ rowsOut) {
    const int b = blockIdx.x;
    const int t = threadIdx.x;  // 0..63
    __shared__ double u[Qn + 1], v[Qn + 1], minv[Qn + 1];
    __shared__ int p[Qn + 1], way[Qn + 1], used[Qn + 1];
    __shared__ int j0s, j1s;
    __shared__ double a[Qn][Pn];

    for (int k = t; k < Qn * Pn; k += 64) a[k / Pn][k % Pn] = (double)cost[b * Qn * Pn + k];
    if (t <= Qn) { u[t] = 0.0; v[t] = 0.0; p[t] = 0; way[t] = 0; }
    __syncthreads();

    for (int i = 1; i <= Qn; ++i) {
        if (t == 0) { p[0] = i; j0s = 0; }
        if (t <= Qn) { minv[t] = 1e18; used[t] = 0; }
        __syncthreads();
        while (true) {
            const int j0 = j0s;
            if (t == 0) used[j0] = 1;
            __syncthreads();
            const int i0 = p[j0];
            double mv = 1e18;
            if (t >= 1 && t <= Qn && !used[t]) {
                double cst = (t - 1 < Pn) ? a[i0 - 1][t - 1] : 1e6;
                double cur = cst - u[i0] - v[t];
                if (cur < minv[t]) { minv[t] = cur; way[t] = j0; }
                mv = minv[t];
            }
            // argmin over lanes; strict < keeps lowest index on ties (matches ref scan)
            double bv = mv; int bj = t;
            for (int off = 32; off > 0; off >>= 1) {
                double ov = __shfl_down(bv, off);
                int    oj = __shfl_down(bj, off);
                if (ov < bv) { bv = ov; bj = oj; }
            }
            double delta = __shfl(bv, 0);
            int    j1    = __shfl(bj, 0);
            if (t <= Qn) {
                if (used[t]) { u[p[t]] += delta; v[t] -= delta; }
                else          minv[t] -= delta;
            }
            __syncthreads();
            if (t == 0) { j1s = j1; j0s = j1; }
            __syncthreads();
            if (p[j0s] == 0) break;
        }
        __syncthreads();
        if (t == 0) {
            int j0 = j0s;
            while (j0) { int j1 = way[j0]; p[j0] = p[j1]; j0 = j1; }
        }
        __syncthreads();
    }
    if (t < Pn) rowsOut[b * Pn + t] = p[t + 1] - 1;
}

// cls + param + pvd in one small block.
__global__ void small_losses_kernel(const float* __restrict__ pred_logits,
                                    const float* __restrict__ ns,
                                    const float* __restrict__ dd,
                                    const float* __restrict__ cham,
                                    const float* __restrict__ cnt,
                                    const int* __restrict__ rows,
                                    float* __restrict__ acc) {
    const int tid = threadIdx.x;
    float cls = 0.f, par = 0.f, pvd = 0.f;
    if (tid < Bn * Qn) {
        int b = tid / Qn, q = tid % Qn;
        float tgt = 0.f;
#pragma unroll
        for (int p = 0; p < Pn; ++p) tgt += (rows[b * Pn + p] == q) ? 1.f : 0.f;
        float x = pred_logits[tid];
        cls = fmaxf(x, 0.f) - x * tgt + log1pf(expf(-fabsf(x)));
    }
    if (tid < Bn * Pn) {
        int b = tid / Pn, p = tid % Pn;
        int r = rows[b * Pn + p];
        int idx = (b * Qn + r) * Pn + p;
        par = ns[idx] + dd[idx];
        pvd = (cnt[b * Pn + p] > 0.f) ? cham[idx] : 0.f;
    }
    __shared__ float sc[256], sp[256], sv[256];
    sc[tid] = cls; sp[tid] = par; sv[tid] = pvd;
    __syncthreads();
    for (int off = 128; off > 0; off >>= 1) {
        if (tid < off) { sc[tid] += sc[tid + off]; sp[tid] += sp[tid + off]; sv[tid] += sv[tid + off]; }
        __syncthreads();
    }
    if (tid == 0) {
        acc[0] = sc[0] / (float)(Bn * Qn);
        acc[1] = sp[0] / (float)(Bn * Pn);
        acc[2] = sv[0] / (float)(Bn * Pn);
    }
}

// One block (one wave) per (b,q) group of 64 points.
__global__ void repulsion_kernel(const float* __restrict__ recon, float* __restrict__ acc) {
    const int g = blockIdx.x;       // b*Qn + q
    const int i = threadIdx.x;      // 0..63
    __shared__ float xs[Fn], ys[Fn], zs[Fn];
    const float* base = recon + (size_t)g * Fn * 3;
    xs[i] = base[i * 3 + 0]; ys[i] = base[i * 3 + 1]; zs[i] = base[i * 3 + 2];
    __syncthreads();
    float best[KNB];
#pragma unroll
    for (int k = 0; k < KNB; ++k) best[k] = 3.4e38f;
    const float xi = xs[i], yi = ys[i], zi = zs[i];
    for (int j = 0; j < Fn; ++j) {
        if (j == i) continue;
        float dx = xi - xs[j], dy = yi - ys[j], dz = zi - zs[j];
        float d2 = dx * dx + dy * dy + dz * dz;
        if (d2 < best[KNB - 1]) {
            int k = KNB - 1;
            while (k > 0 && best[k - 1] > d2) { best[k] = best[k - 1]; --k; }
            best[k] = d2;
        }
    }
    float sum = 0.f;
#pragma unroll
    for (int k = 0; k < KNB; ++k) {
        float dn = fmaxf(best[k], 1e-12f);
        float w  = expf(-dn / (0.03f * 0.03f));
        sum += (0.07f - sqrtf(dn)) * w;
    }
    for (int off = 32; off > 0; off >>= 1) sum += __shfl_down(sum, off);
    if (i == 0) {
        float mean = sum / (float)(Fn * KNB);
        atomicAdd(&acc[3], fmaxf(mean, 0.f) / (float)(Bn * Qn));
    }
}

// Direction A: per reconstructed point, min over gt cloud (LDS-tiled).
__global__ void chamferA_kernel(const float* __restrict__ recon, const float* __restrict__ gt,
                                float* __restrict__ acc) {
    const int idx = blockIdx.x * 256 + threadIdx.x;  // over B*M; blocks never straddle b
    const int b = idx / Mn;
    const float x = recon[idx * 3 + 0], y = recon[idx * 3 + 1], z = recon[idx * 3 + 2];
    const float* gb = gt + (size_t)b * Gn * 3;
    __shared__ float tx[256], ty[256], tz[256];
    float m1 = 3.4e38f, m2 = 3.4e38f;
    for (int t0 = 0; t0 < Gn; t0 += 256) {
        int j = t0 + threadIdx.x;
        tx[threadIdx.x] = gb[j * 3 + 0];
        ty[threadIdx.x] = gb[j * 3 + 1];
        tz[threadIdx.x] = gb[j * 3 + 2];
        __syncthreads();
        for (int j2 = 0; j2 < 256; ++j2) {
            float dx = x - tx[j2], dy = y - ty[j2], dz = z - tz[j2];
            float d1 = fabsf(dx) + fabsf(dy) + fabsf(dz);
            float d2 = dx * dx + dy * dy + dz * dz;
            m1 = fminf(m1, d1); m2 = fminf(m2, d2);
        }
        __syncthreads();
    }
    __shared__ float s1[256], s2[256];
    s1[threadIdx.x] = m1; s2[threadIdx.x] = m2;
    __syncthreads();
    for (int off = 128; off > 0; off >>= 1) {
        if (threadIdx.x < off) { s1[threadIdx.x] += s1[threadIdx.x + off]; s2[threadIdx.x] += s2[threadIdx.x + off]; }
        __syncthreads();
    }
    if (threadIdx.x == 0) {
        atomicAdd(&acc[4], s1[0] * (0.5f / (float)(Bn * Mn)));
        atomicAdd(&acc[5], s2[0] * (0.5f / (float)(Bn * Mn)));
    }
}

// Direction B: per gt point, min over reconstructed cloud (LDS-tiled).
__global__ void chamferB_kernel(const float* __restrict__ recon, const float* __restrict__ gt,
                                float* __restrict__ acc) {
    const int idx = blockIdx.x * 256 + threadIdx.x;  // over B*G; blocks never straddle b
    const int b = idx / Gn;
    const float x = gt[idx * 3 + 0], y = gt[idx * 3 + 1], z = gt[idx * 3 + 2];
    const float* rb = recon + (size_t)b * Mn * 3;
    __shared__ float tx[256], ty[256], tz[256];
    float m1 = 3.4e38f, m2 = 3.4e38f;
    for (int t0 = 0; t0 < Mn; t0 += 256) {
        int j = t0 + threadIdx.x;
        tx[threadIdx.x] = rb[j * 3 + 0];
        ty[threadIdx.x] = rb[j * 3 + 1];
        tz[threadIdx.x] = rb[j * 3 + 2];
        __syncthreads();
        for (int j2 = 0; j2 < 256; ++j2) {
            float dx = x - tx[j2], dy = y - ty[j2], dz = z - tz[j2];
            float d1 = fabsf(dx) + fabsf(dy) + fabsf(dz);
            float d2 = dx * dx + dy * dy + dz * dz;
            m1 = fminf(m1, d1); m2 = fminf(m2, d2);
        }
        __syncthreads();
    }
    __shared__ float s1[256], s2[256];
    s1[threadIdx.x] = m1; s2[threadIdx.x] = m2;
    __syncthreads();
    for (int off = 128; off > 0; off >>= 1) {
        if (threadIdx.x < off) { s1[threadIdx.x] += s1[threadIdx.x + off]; s2[threadIdx.x] += s2[threadIdx.x + off]; }
        __syncthreads();
    }
    if (threadIdx.x == 0) {
        atomicAdd(&acc[4], s1[0] * (0.5f / (float)(Bn * Gn)));
        atomicAdd(&acc[5], s2[0] * (0.5f / (float)(Bn * Gn)));
    }
}

__global__ void finalize_kernel(const float* __restrict__ acc, float* __restrict__ out) {
    out[0] = acc[0] + 0.5f * acc[1] + 20.f * acc[2] + acc[3] + acc[4] + acc[5];
}

extern "C" void kernel_launch(void* const* d_in, const int* in_sizes, int n_in,
                              void* d_out, int out_size, void* d_ws, size_t ws_size,
                              hipStream_t stream) {
    const float* pred_logits    = (const float*)d_in[0];
    const float* pred_normals   = (const float*)d_in[1];
    const float* pred_distances = (const float*)d_in[2];
    const float* gt_normals     = (const float*)d_in[3];
    const float* gt_distances   = (const float*)d_in[4];
    const int*   gt_masks       = (const int*)d_in[5];
    const float* points         = (const float*)d_in[6];
    const float* recon          = (const float*)d_in[7];
    const float* gt             = (const float*)d_in[8];
    // d_in[9] (gt_index) is unused by the reference.

    float* ws   = (float*)d_ws;
    float* cham = ws;
    float* ns   = ws + 1920;
    float* dd   = ws + 3840;
    float* cost = ws + 5760;
    float* cnt  = ws + 7680;
    int*   rows = (int*)(ws + 7776);
    float* acc  = ws + 7872;

    zero_acc_kernel<<<1, 64, 0, stream>>>(acc);
    cost_kernel<<<Bn * Qn, 256, 0, stream>>>(pred_normals, pred_distances, gt_normals,
                                             gt_distances, points, gt_masks,
                                             cham, ns, dd, cost, cnt);
    hungarian_kernel<<<Bn, 64, 0, stream>>>(cost, rows);
    small_losses_kernel<<<1, 256, 0, stream>>>(pred_logits, ns, dd, cham, cnt, rows, acc);
    repulsion_kernel<<<Bn * Qn, Fn, 0, stream>>>(recon, acc);
    chamferA_kernel<<<(Bn * Mn) / 256, 256, 0, stream>>>(recon, gt, acc);
    chamferB_kernel<<<(Bn * Gn) / 256, 256, 0, stream>>>(recon, gt, acc);
    finalize_kernel<<<1, 1, 0, stream>>>(acc, (float*)d_out);
}

// Round 2
// 166.164 us; speedup vs baseline: 2.1676x; 2.1676x over previous
//
#include <hip/hip_runtime.h>
#include <math.h>

#define Bn 8
#define Qn 20
#define Pn 12
#define Nn 4096
#define Gn 2048
#define Mn 1280   /* Q*FACTOR */
#define Fn 64
#define KNB 7     /* K_NEIGHBORS - 1 */
#define SA 8      /* gt splits for chamfer A (2048/256)  */
#define SB 5      /* recon splits for chamfer B (1280/256) */

// ---------------- workspace layout (float units) ----------------
// cham : [0,      1920)   (B,Q,P)
// ns   : [1920,   3840)
// dd   : [3840,   5760)
// cost : [5760,   7680)
// cnt  : [7680,   7776)   (B,P)
// rows : [7776,   7872)   int (B,P)
// acc  : [7872,   7888)   scalars: 0 cls, 1 param, 2 pvd, 3 rep, 4 ch1, 5 ch2
// pmA1 : [8192,   90112)   (SA, B*M)
// pmA2 : [90112, 172032)
// pmB1 : [172032,253952)   (SB, B*G)
// pmB2 : [253952,335872)

__global__ void zero_acc_kernel(float* acc) {
    if (threadIdx.x < 16) acc[threadIdx.x] = 0.f;
}

// One block per (b,q); computes cham_raw, normal_sim, dist_diff, cost for all p,
// plus mask counts (written once by the q==0 block).
__global__ void cost_kernel(const float* __restrict__ pred_normals,
                            const float* __restrict__ pred_distances,
                            const float* __restrict__ gt_normals,
                            const float* __restrict__ gt_distances,
                            const float* __restrict__ points,
                            const int*   __restrict__ gt_masks,
                            float* __restrict__ cham, float* __restrict__ ns,
                            float* __restrict__ dd, float* __restrict__ cost,
                            float* __restrict__ cnt) {
    const int bq = blockIdx.x;
    const int b = bq / Qn, q = bq % Qn;
    const int tid = threadIdx.x;

    const float nx = pred_normals[(b * Qn + q) * 3 + 0];
    const float ny = pred_normals[(b * Qn + q) * 3 + 1];
    const float nz = pred_normals[(b * Qn + q) * 3 + 2];
    const float dq = pred_distances[b * Qn + q];

    float accs[Pn], accw[Pn];
#pragma unroll
    for (int p = 0; p < Pn; ++p) { accs[p] = 0.f; accw[p] = 0.f; }

    const float* ptb = points + (size_t)b * Nn * 3;
    const int*   mb  = gt_masks + (size_t)b * Pn * Nn;

    for (int n = tid; n < Nn; n += 256) {
        float px = ptb[n * 3 + 0], py = ptb[n * 3 + 1], pz = ptb[n * 3 + 2];
        float pp = fabsf(px * nx + py * ny + pz * nz - dq);
#pragma unroll
        for (int p = 0; p < Pn; ++p) {
            float m = (float)mb[(size_t)p * Nn + n];
            accs[p] += pp * m;
            accw[p] += m;
        }
    }

    __shared__ float s[2 * Pn][256];
#pragma unroll
    for (int p = 0; p < Pn; ++p) { s[p][tid] = accs[p]; s[p + Pn][tid] = accw[p]; }
    __syncthreads();
    for (int off = 128; off > 0; off >>= 1) {
        if (tid < off) {
#pragma unroll
            for (int r = 0; r < 2 * Pn; ++r) s[r][tid] += s[r][tid + off];
        }
        __syncthreads();
    }

    if (tid < Pn) {
        const int p = tid;
        float c  = s[p + Pn][0];
        float cv = s[p][0] / fmaxf(c, 1.f);
        float gnx = gt_normals[(b * Pn + p) * 3 + 0];
        float gny = gt_normals[(b * Pn + p) * 3 + 1];
        float gnz = gt_normals[(b * Pn + p) * 3 + 2];
        float nsim = 1.f - fabsf(nx * gnx + ny * gny + nz * gnz);
        float ddv  = fabsf(dq - gt_distances[b * Pn + p]);
        int idx = (b * Qn + q) * Pn + p;
        cham[idx] = cv;
        ns[idx]   = nsim;
        dd[idx]   = ddv;
        cost[idx] = nsim + 0.5f * ddv + 5.f * ((c > 0.f) ? cv : 1.f);
        if (q == 0) cnt[b * Pn + p] = c;
    }
}

// Wave-parallel Jonker-Volgenant, TRANSPOSED rectangular 12x20 (gt rows, query cols).
// Equivalent to the reference's 20x20 pad-to-square (pad columns are interchangeable,
// so the optimal real matching is identical for generic costs). All per-column and
// per-row state in registers; cross-lane via shuffles; cost matrix read-only in LDS;
// NO barriers in the serial loop. f64 arithmetic, same update order as reference.
__global__ void hungarian_kernel(const float* __restrict__ cost, int* __restrict__ rowsOut) {
    const int b = blockIdx.x;
    const int t = threadIdx.x;  // 0..63
    __shared__ double a[Pn * Qn];  // a[i*Qn + j] = cost[b][q=j][p=i]
    for (int k = t; k < Qn * Pn; k += 64)
        a[(k % Pn) * Qn + (k / Pn)] = (double)cost[b * Qn * Pn + k];
    __syncthreads();

    const int col = t;                       // lane owns column col (1..20 valid)
    const bool isCol = (col >= 1 && col <= Qn);
    double v = 0.0;                          // v[col]
    double u = 0.0;                          // u[row], row == lane (1..12 valid)
    double minv = 0.0;
    int way = 0, p = 0;                      // per-column state

    for (int i = 1; i <= Pn; ++i) {
        const int p0 = i;
        minv = 1e18;
        bool used = false;
        bool rowInPath = false;
        int j0 = 0;
        while (true) {
            if (col == j0) used = true;
            int i0 = (j0 == 0) ? p0 : __shfl(p, j0);
            if (t == i0) rowInPath = true;
            double u_i0 = __shfl(u, i0);
            double mv = 1e18;
            if (isCol && !used) {
                double cur = a[(i0 - 1) * Qn + (col - 1)] - u_i0 - v;
                if (cur < minv) { minv = cur; way = j0; }
                mv = minv;
            }
            // argmin over lanes 0..31 (others hold 1e18); strict < keeps lowest index on ties
            double bv = mv; int bj = col;
#pragma unroll
            for (int off = 16; off > 0; off >>= 1) {
                double ov = __shfl_down(bv, off);
                int    oj = __shfl_down(bj, off);
                if (ov < bv) { bv = ov; bj = oj; }
            }
            double delta = __shfl(bv, 0);
            int    j1    = __shfl(bj, 0);
            if (used || col == 0) v -= delta;      // used columns: v[j] -= delta
            else if (isCol)       minv -= delta;   // unused: minv[j] -= delta
            if (rowInPath)        u += delta;      // rows on path: u[p[j]] += delta
            j0 = j1;
            int pj0 = __shfl(p, j0);
            if (pj0 == 0) break;
        }
        // augment: while j0: j1=way[j0]; p[j0]=p[j1]; j0=j1
        while (j0 != 0) {
            int wj = __shfl(way, j0);
            int pw = (wj == 0) ? p0 : __shfl(p, wj);
            if (col == j0) p = pw;
            j0 = wj;
        }
    }
    if (isCol && p > 0) rowsOut[b * Pn + (p - 1)] = col - 1;
}

// cls + param + pvd in one small block.
__global__ void small_losses_kernel(const float* __restrict__ pred_logits,
                                    const float* __restrict__ ns,
                                    const float* __restrict__ dd,
                                    const float* __restrict__ cham,
                                    const float* __restrict__ cnt,
                                    const int* __restrict__ rows,
                                    float* __restrict__ acc) {
    const int tid = threadIdx.x;
    float cls = 0.f, par = 0.f, pvd = 0.f;
    if (tid < Bn * Qn) {
        int b = tid / Qn, q = tid % Qn;
        float tgt = 0.f;
#pragma unroll
        for (int p = 0; p < Pn; ++p) tgt += (rows[b * Pn + p] == q) ? 1.f : 0.f;
        float x = pred_logits[tid];
        cls = fmaxf(x, 0.f) - x * tgt + log1pf(expf(-fabsf(x)));
    }
    if (tid < Bn * Pn) {
        int b = tid / Pn, p = tid % Pn;
        int r = rows[b * Pn + p];
        int idx = (b * Qn + r) * Pn + p;
        par = ns[idx] + dd[idx];
        pvd = (cnt[b * Pn + p] > 0.f) ? cham[idx] : 0.f;
    }
    __shared__ float sc[256], sp[256], sv[256];
    sc[tid] = cls; sp[tid] = par; sv[tid] = pvd;
    __syncthreads();
    for (int off = 128; off > 0; off >>= 1) {
        if (tid < off) { sc[tid] += sc[tid + off]; sp[tid] += sp[tid + off]; sv[tid] += sv[tid + off]; }
        __syncthreads();
    }
    if (tid == 0) {
        acc[0] = sc[0] / (float)(Bn * Qn);
        acc[1] = sp[0] / (float)(Bn * Pn);
        acc[2] = sv[0] / (float)(Bn * Pn);
    }
}

// One block (one wave) per (b,q) group of 64 points.
__global__ void repulsion_kernel(const float* __restrict__ recon, float* __restrict__ acc) {
    const int g = blockIdx.x;       // b*Qn + q
    const int i = threadIdx.x;      // 0..63
    __shared__ float xs[Fn], ys[Fn], zs[Fn];
    const float* base = recon + (size_t)g * Fn * 3;
    xs[i] = base[i * 3 + 0]; ys[i] = base[i * 3 + 1]; zs[i] = base[i * 3 + 2];
    __syncthreads();
    float best[KNB];
#pragma unroll
    for (int k = 0; k < KNB; ++k) best[k] = 3.4e38f;
    const float xi = xs[i], yi = ys[i], zi = zs[i];
    for (int j = 0; j < Fn; ++j) {
        if (j == i) continue;
        float dx = xi - xs[j], dy = yi - ys[j], dz = zi - zs[j];
        float d2 = dx * dx + dy * dy + dz * dz;
        if (d2 < best[KNB - 1]) {
            int k = KNB - 1;
            while (k > 0 && best[k - 1] > d2) { best[k] = best[k - 1]; --k; }
            best[k] = d2;
        }
    }
    float sum = 0.f;
#pragma unroll
    for (int k = 0; k < KNB; ++k) {
        float dn = fmaxf(best[k], 1e-12f);
        float w  = expf(-dn / (0.03f * 0.03f));
        sum += (0.07f - sqrtf(dn)) * w;
    }
    for (int off = 32; off > 0; off >>= 1) sum += __shfl_down(sum, off);
    if (i == 0) {
        float mean = sum / (float)(Fn * KNB);
        atomicAdd(&acc[3], fmaxf(mean, 0.f) / (float)(Bn * Qn));
    }
}

// Phase 1: partial mins over 256-point chunks of the opposite cloud.
// blocks [0, 40*SA): direction A (outer = recon, inner = gt chunk)
// blocks [40*SA, 40*SA + 64*SB): direction B (outer = gt, inner = recon chunk)
__global__ void chamfer_partial_kernel(const float* __restrict__ recon,
                                       const float* __restrict__ gt,
                                       float* __restrict__ pmA1, float* __restrict__ pmA2,
                                       float* __restrict__ pmB1, float* __restrict__ pmB2) {
    __shared__ float tx[256], ty[256], tz[256];
    int blk = blockIdx.x;
    const int tid = threadIdx.x;
    float x, y, z;
    const float* inner;
    float *o1, *o2;
    int idx;
    if (blk < 40 * SA) {
        int s = blk % SA, ob = blk / SA;
        idx = ob * 256 + tid;                 // over B*M (1280 % 256 == 0: no straddle)
        int b = idx / Mn;
        x = recon[idx * 3 + 0]; y = recon[idx * 3 + 1]; z = recon[idx * 3 + 2];
        inner = gt + ((size_t)b * Gn + s * 256) * 3;
        o1 = pmA1 + s * (Bn * Mn); o2 = pmA2 + s * (Bn * Mn);
    } else {
        blk -= 40 * SA;
        int s = blk % SB, ob = blk / SB;
        idx = ob * 256 + tid;                 // over B*G
        int b = idx / Gn;
        x = gt[idx * 3 + 0]; y = gt[idx * 3 + 1]; z = gt[idx * 3 + 2];
        inner = recon + ((size_t)b * Mn + s * 256) * 3;
        o1 = pmB1 + s * (Bn * Gn); o2 = pmB2 + s * (Bn * Gn);
    }
    tx[tid] = inner[tid * 3 + 0];
    ty[tid] = inner[tid * 3 + 1];
    tz[tid] = inner[tid * 3 + 2];
    __syncthreads();
    float m1 = 3.4e38f, m2 = 3.4e38f;
    for (int j = 0; j < 256; ++j) {
        float dx = x - tx[j], dy = y - ty[j], dz = z - tz[j];
        float d1 = fabsf(dx) + fabsf(dy) + fabsf(dz);
        float d2 = dx * dx + dy * dy + dz * dz;
        m1 = fminf(m1, d1); m2 = fminf(m2, d2);
    }
    o1[idx] = m1; o2[idx] = m2;
}

// Phase 2: combine partial mins, weighted block-sum into acc.
// blocks [0,40): A points (B*M); blocks [40,104): B points (B*G)
__global__ void chamfer_reduce_kernel(const float* __restrict__ pmA1, const float* __restrict__ pmA2,
                                      const float* __restrict__ pmB1, const float* __restrict__ pmB2,
                                      float* __restrict__ acc) {
    const int blk = blockIdx.x;
    const int tid = threadIdx.x;
    float c1, c2;
    if (blk < 40) {
        int idx = blk * 256 + tid;
        float m1 = 3.4e38f, m2 = 3.4e38f;
#pragma unroll
        for (int s = 0; s < SA; ++s) {
            m1 = fminf(m1, pmA1[s * (Bn * Mn) + idx]);
            m2 = fminf(m2, pmA2[s * (Bn * Mn) + idx]);
        }
        c1 = m1 * (0.5f / (float)(Bn * Mn));
        c2 = m2 * (0.5f / (float)(Bn * Mn));
    } else {
        int idx = (blk - 40) * 256 + tid;
        float m1 = 3.4e38f, m2 = 3.4e38f;
#pragma unroll
        for (int s = 0; s < SB; ++s) {
            m1 = fminf(m1, pmB1[s * (Bn * Gn) + idx]);
            m2 = fminf(m2, pmB2[s * (Bn * Gn) + idx]);
        }
        c1 = m1 * (0.5f / (float)(Bn * Gn));
        c2 = m2 * (0.5f / (float)(Bn * Gn));
    }
    __shared__ float s1[256], s2[256];
    s1[tid] = c1; s2[tid] = c2;
    __syncthreads();
    for (int off = 128; off > 0; off >>= 1) {
        if (tid < off) { s1[tid] += s1[tid + off]; s2[tid] += s2[tid + off]; }
        __syncthreads();
    }
    if (tid == 0) {
        atomicAdd(&acc[4], s1[0]);
        atomicAdd(&acc[5], s2[0]);
    }
}

__global__ void finalize_kernel(const float* __restrict__ acc, float* __restrict__ out) {
    out[0] = acc[0] + 0.5f * acc[1] + 20.f * acc[2] + acc[3] + acc[4] + acc[5];
}

extern "C" void kernel_launch(void* const* d_in, const int* in_sizes, int n_in,
                              void* d_out, int out_size, void* d_ws, size_t ws_size,
                              hipStream_t stream) {
    const float* pred_logits    = (const float*)d_in[0];
    const float* pred_normals   = (const float*)d_in[1];
    const float* pred_distances = (const float*)d_in[2];
    const float* gt_normals     = (const float*)d_in[3];
    const float* gt_distances   = (const float*)d_in[4];
    const int*   gt_masks       = (const int*)d_in[5];
    const float* points         = (const float*)d_in[6];
    const float* recon          = (const float*)d_in[7];
    const float* gt             = (const float*)d_in[8];
    // d_in[9] (gt_index) is unused by the reference.

    float* ws   = (float*)d_ws;
    float* cham = ws;
    float* ns   = ws + 1920;
    float* dd   = ws + 3840;
    float* cost = ws + 5760;
    float* cnt  = ws + 7680;
    int*   rows = (int*)(ws + 7776);
    float* acc  = ws + 7872;
    float* pmA1 = ws + 8192;
    float* pmA2 = ws + 90112;
    float* pmB1 = ws + 172032;
    float* pmB2 = ws + 253952;

    zero_acc_kernel<<<1, 64, 0, stream>>>(acc);
    cost_kernel<<<Bn * Qn, 256, 0, stream>>>(pred_normals, pred_distances, gt_normals,
                                             gt_distances, points, gt_masks,
                                             cham, ns, dd, cost, cnt);
    hungarian_kernel<<<Bn, 64, 0, stream>>>(cost, rows);
    small_losses_kernel<<<1, 256, 0, stream>>>(pred_logits, ns, dd, cham, cnt, rows, acc);
    repulsion_kernel<<<Bn * Qn, Fn, 0, stream>>>(recon, acc);
    chamfer_partial_kernel<<<40 * SA + 64 * SB, 256, 0, stream>>>(recon, gt, pmA1, pmA2, pmB1, pmB2);
    chamfer_reduce_kernel<<<104, 256, 0, stream>>>(pmA1, pmA2, pmB1, pmB2, acc);
    finalize_kernel<<<1, 1, 0, stream>>>(acc, (float*)d_out);
}

// Round 3
// 135.437 us; speedup vs baseline: 2.6593x; 1.2269x over previous
//
#include <hip/hip_runtime.h>
#include <math.h>

#define Bn 8
#define Qn 20
#define Pn 12
#define Nn 4096
#define Gn 2048
#define Mn 1280   /* Q*FACTOR */
#define Fn 64
#define KNB 7     /* K_NEIGHBORS - 1 */
#define SA 8      /* gt splits for chamfer A (2048/256)  */
#define SB 5      /* recon splits for chamfer B (1280/256) */

// ---------------- workspace layout (float units) ----------------
// cham : [0,      1920)   (B,Q,P)
// ns   : [1920,   3840)
// dd   : [3840,   5760)
// cost : [5760,   7680)
// cnt  : [7680,   7776)   (B,P)
// acc  : [7872,   7888)   0 cls, 1 param, 2 pvd, 3 rep, 4 ch1, 5 ch2
// cntr : [7888]           int completion counter for K3
// rep  : [7904,   8064)   per-group repulsion partials (160)
// pmA1 : [8192,   90112)   (SA, B*M)
// pmA2 : [90112, 172032)
// pmB1 : [172032,253952)   (SB, B*G)
// pmB2 : [253952,335872)

// ============ K1: cost (160) + repulsion (40) + chamfer partials (640) ============
__global__ void mega1_kernel(const float* __restrict__ pred_normals,
                             const float* __restrict__ pred_distances,
                             const float* __restrict__ gt_normals,
                             const float* __restrict__ gt_distances,
                             const float* __restrict__ points,
                             const int*   __restrict__ gt_masks,
                             const float* __restrict__ recon,
                             const float* __restrict__ gt,
                             float* __restrict__ cham, float* __restrict__ ns,
                             float* __restrict__ dd, float* __restrict__ cost,
                             float* __restrict__ cnt, float* __restrict__ acc,
                             float* __restrict__ rep_part,
                             float* __restrict__ pmA1, float* __restrict__ pmA2,
                             float* __restrict__ pmB1, float* __restrict__ pmB2) {
    __shared__ float smem[2 * Pn * 256];
    const int blk = blockIdx.x;
    const int tid = threadIdx.x;

    if (blk < 160) {
        // ---- cost path: one block per (b,q) ----
        if (blk == 0 && tid < 20) acc[tid] = 0.f;  // zero acc[0..15] + counter + spare
        const int b = blk / Qn, q = blk % Qn;
        const float nx = pred_normals[(b * Qn + q) * 3 + 0];
        const float ny = pred_normals[(b * Qn + q) * 3 + 1];
        const float nz = pred_normals[(b * Qn + q) * 3 + 2];
        const float dq = pred_distances[b * Qn + q];

        float accs[Pn], accw[Pn];
#pragma unroll
        for (int p = 0; p < Pn; ++p) { accs[p] = 0.f; accw[p] = 0.f; }

        const float* ptb = points + (size_t)b * Nn * 3;
        const int*   mb  = gt_masks + (size_t)b * Pn * Nn;

        for (int n = tid; n < Nn; n += 256) {
            float px = ptb[n * 3 + 0], py = ptb[n * 3 + 1], pz = ptb[n * 3 + 2];
            float pp = fabsf(px * nx + py * ny + pz * nz - dq);
#pragma unroll
            for (int p = 0; p < Pn; ++p) {
                float m = (float)mb[(size_t)p * Nn + n];
                accs[p] += pp * m;
                accw[p] += m;
            }
        }
#pragma unroll
        for (int p = 0; p < Pn; ++p) {
            smem[p * 256 + tid] = accs[p];
            smem[(p + Pn) * 256 + tid] = accw[p];
        }
        __syncthreads();
        for (int off = 128; off > 0; off >>= 1) {
            if (tid < off) {
#pragma unroll
                for (int r = 0; r < 2 * Pn; ++r) smem[r * 256 + tid] += smem[r * 256 + tid + off];
            }
            __syncthreads();
        }
        if (tid < Pn) {
            const int p = tid;
            float c  = smem[(p + Pn) * 256];
            float cv = smem[p * 256] / fmaxf(c, 1.f);
            float gnx = gt_normals[(b * Pn + p) * 3 + 0];
            float gny = gt_normals[(b * Pn + p) * 3 + 1];
            float gnz = gt_normals[(b * Pn + p) * 3 + 2];
            float nsim = 1.f - fabsf(nx * gnx + ny * gny + nz * gnz);
            float ddv  = fabsf(dq - gt_distances[b * Pn + p]);
            int idx = (b * Qn + q) * Pn + p;
            cham[idx] = cv;
            ns[idx]   = nsim;
            dd[idx]   = ddv;
            cost[idx] = nsim + 0.5f * ddv + 5.f * ((c > 0.f) ? cv : 1.f);
            if (q == 0) cnt[b * Pn + p] = c;
        }
    } else if (blk < 200) {
        // ---- repulsion path: 4 waves per block, one (b,q) group of 64 pts per wave ----
        const int wave = tid >> 6, lane = tid & 63;
        const int g = (blk - 160) * 4 + wave;
        float* xs = smem + wave * 192;
        float* ys = xs + 64;
        float* zs = xs + 128;
        const float* base = recon + (size_t)g * Fn * 3;
        xs[lane] = base[lane * 3 + 0];
        ys[lane] = base[lane * 3 + 1];
        zs[lane] = base[lane * 3 + 2];
        __syncthreads();
        float best[KNB];
#pragma unroll
        for (int k = 0; k < KNB; ++k) best[k] = 3.4e38f;
        const float xi = xs[lane], yi = ys[lane], zi = zs[lane];
        for (int j = 0; j < Fn; ++j) {
            if (j == lane) continue;
            float dx = xi - xs[j], dy = yi - ys[j], dz = zi - zs[j];
            float d2 = dx * dx + dy * dy + dz * dz;
            if (d2 < best[KNB - 1]) {
                int k = KNB - 1;
                while (k > 0 && best[k - 1] > d2) { best[k] = best[k - 1]; --k; }
                best[k] = d2;
            }
        }
        float sum = 0.f;
#pragma unroll
        for (int k = 0; k < KNB; ++k) {
            float dn = fmaxf(best[k], 1e-12f);
            float w  = expf(-dn / (0.03f * 0.03f));
            sum += (0.07f - sqrtf(dn)) * w;
        }
        for (int off = 32; off > 0; off >>= 1) sum += __shfl_down(sum, off);
        if (lane == 0) rep_part[g] = fmaxf(sum / (float)(Fn * KNB), 0.f);
    } else {
        // ---- chamfer partial path ----
        int cblk = blk - 200;
        float* tx = smem;
        float* ty = smem + 256;
        float* tz = smem + 512;
        float x, y, z;
        const float* inner;
        float *o1, *o2;
        int idx;
        if (cblk < 40 * SA) {
            int s = cblk % SA, ob = cblk / SA;
            idx = ob * 256 + tid;                 // over B*M
            int b = idx / Mn;
            x = recon[idx * 3 + 0]; y = recon[idx * 3 + 1]; z = recon[idx * 3 + 2];
            inner = gt + ((size_t)b * Gn + s * 256) * 3;
            o1 = pmA1 + s * (Bn * Mn); o2 = pmA2 + s * (Bn * Mn);
        } else {
            cblk -= 40 * SA;
            int s = cblk % SB, ob = cblk / SB;
            idx = ob * 256 + tid;                 // over B*G
            int b = idx / Gn;
            x = gt[idx * 3 + 0]; y = gt[idx * 3 + 1]; z = gt[idx * 3 + 2];
            inner = recon + ((size_t)b * Mn + s * 256) * 3;
            o1 = pmB1 + s * (Bn * Gn); o2 = pmB2 + s * (Bn * Gn);
        }
        tx[tid] = inner[tid * 3 + 0];
        ty[tid] = inner[tid * 3 + 1];
        tz[tid] = inner[tid * 3 + 2];
        __syncthreads();
        float m1 = 3.4e38f, m2 = 3.4e38f;
        for (int j = 0; j < 256; ++j) {
            float dx = x - tx[j], dy = y - ty[j], dz = z - tz[j];
            float d1 = fabsf(dx) + fabsf(dy) + fabsf(dz);
            float d2 = dx * dx + dy * dy + dz * dz;
            m1 = fminf(m1, d1); m2 = fminf(m2, d2);
        }
        o1[idx] = m1; o2[idx] = m2;
    }
}

// ============ K2: Hungarian (transposed rectangular JV) + cls/param/pvd fused ============
// One wave per batch. All state in registers, cross-lane via shuffles, no loop barriers.
// Transposed 12x20 is equivalent to the reference's pad-to-square 20x20 (pad columns are
// interchangeable => identical real matching for generic costs). f64, reference update order.
__global__ void hungarian_kernel(const float* __restrict__ cost,
                                 const float* __restrict__ pred_logits,
                                 const float* __restrict__ ns,
                                 const float* __restrict__ dd,
                                 const float* __restrict__ cham,
                                 const float* __restrict__ cnt,
                                 float* __restrict__ acc) {
    const int b = blockIdx.x;
    const int t = threadIdx.x;  // 0..63
    __shared__ double a[Pn * Qn];  // a[i*Qn + j] = cost[b][q=j][p=i]
    for (int k = t; k < Qn * Pn; k += 64)
        a[(k % Pn) * Qn + (k / Pn)] = (double)cost[b * Qn * Pn + k];
    __syncthreads();

    const int col = t;                       // lane owns column col (1..20 valid)
    const bool isCol = (col >= 1 && col <= Qn);
    double v = 0.0;                          // v[col]
    double u = 0.0;                          // u[row], row == lane (1..12 valid)
    double minv = 0.0;
    int way = 0, p = 0;                      // per-column state

    for (int i = 1; i <= Pn; ++i) {
        const int p0 = i;
        minv = 1e18;
        bool used = false;
        bool rowInPath = false;
        int j0 = 0;
        while (true) {
            if (col == j0) used = true;
            int i0 = (j0 == 0) ? p0 : __shfl(p, j0);
            if (t == i0) rowInPath = true;
            double u_i0 = __shfl(u, i0);
            double mv = 1e18;
            if (isCol && !used) {
                double cur = a[(i0 - 1) * Qn + (col - 1)] - u_i0 - v;
                if (cur < minv) { minv = cur; way = j0; }
                mv = minv;
            }
            double bv = mv; int bj = col;
#pragma unroll
            for (int off = 16; off > 0; off >>= 1) {
                double ov = __shfl_down(bv, off);
                int    oj = __shfl_down(bj, off);
                if (ov < bv) { bv = ov; bj = oj; }
            }
            double delta = __shfl(bv, 0);
            int    j1    = __shfl(bj, 0);
            if (used || col == 0) v -= delta;
            else if (isCol)       minv -= delta;
            if (rowInPath)        u += delta;
            j0 = j1;
            int pj0 = __shfl(p, j0);
            if (pj0 == 0) break;
        }
        while (j0 != 0) {
            int wj = __shfl(way, j0);
            int pw = (wj == 0) ? p0 : __shfl(p, wj);
            if (col == j0) p = pw;
            j0 = wj;
        }
    }

    // ---- fused small losses: lane col holds its match (row p, col) ----
    float cls = 0.f, par = 0.f, pvd = 0.f;
    if (isCol) {
        float x = pred_logits[b * Qn + (col - 1)];
        float tgt = (p > 0) ? 1.f : 0.f;
        cls = fmaxf(x, 0.f) - x * tgt + log1pf(expf(-fabsf(x)));
        if (p > 0) {
            int idx = (b * Qn + (col - 1)) * Pn + (p - 1);
            par = ns[idx] + dd[idx];
            pvd = (cnt[b * Pn + (p - 1)] > 0.f) ? cham[idx] : 0.f;
        }
    }
    for (int off = 32; off > 0; off >>= 1) {
        cls += __shfl_down(cls, off);
        par += __shfl_down(par, off);
        pvd += __shfl_down(pvd, off);
    }
    if (t == 0) {
        atomicAdd(&acc[0], cls / (float)(Bn * Qn));
        atomicAdd(&acc[1], par / (float)(Bn * Pn));
        atomicAdd(&acc[2], pvd / (float)(Bn * Pn));
    }
}

// ============ K3: chamfer reduce + repulsion reduce + last-block finalize ============
// blocks [0,40): A points; [40,104): B points; 104: repulsion partials.
__global__ void reduce_kernel(const float* __restrict__ pmA1, const float* __restrict__ pmA2,
                              const float* __restrict__ pmB1, const float* __restrict__ pmB2,
                              const float* __restrict__ rep_part,
                              float* __restrict__ acc, int* __restrict__ counter,
                              float* __restrict__ out) {
    const int blk = blockIdx.x;
    const int tid = threadIdx.x;
    float c1 = 0.f, c2 = 0.f;
    if (blk < 40) {
        int idx = blk * 256 + tid;
        float m1 = 3.4e38f, m2 = 3.4e38f;
#pragma unroll
        for (int s = 0; s < SA; ++s) {
            m1 = fminf(m1, pmA1[s * (Bn * Mn) + idx]);
            m2 = fminf(m2, pmA2[s * (Bn * Mn) + idx]);
        }
        c1 = m1 * (0.5f / (float)(Bn * Mn));
        c2 = m2 * (0.5f / (float)(Bn * Mn));
    } else if (blk < 104) {
        int idx = (blk - 40) * 256 + tid;
        float m1 = 3.4e38f, m2 = 3.4e38f;
#pragma unroll
        for (int s = 0; s < SB; ++s) {
            m1 = fminf(m1, pmB1[s * (Bn * Gn) + idx]);
            m2 = fminf(m2, pmB2[s * (Bn * Gn) + idx]);
        }
        c1 = m1 * (0.5f / (float)(Bn * Gn));
        c2 = m2 * (0.5f / (float)(Bn * Gn));
    } else {
        c1 = (tid < Bn * Qn) ? rep_part[tid] / (float)(Bn * Qn) : 0.f;
    }
    __shared__ float s1[256], s2[256];
    s1[tid] = c1; s2[tid] = c2;
    __syncthreads();
    for (int off = 128; off > 0; off >>= 1) {
        if (tid < off) { s1[tid] += s1[tid + off]; s2[tid] += s2[tid + off]; }
        __syncthreads();
    }
    if (tid == 0) {
        if (blk < 104) {
            atomicAdd(&acc[4], s1[0]);
            atomicAdd(&acc[5], s2[0]);
        } else {
            atomicAdd(&acc[3], s1[0]);
        }
        __threadfence();
        int old = atomicAdd(counter, 1);
        if (old == 104) {
            // all 105 blocks done; device-scope atomic reads of acc
            float a0 = atomicAdd(&acc[0], 0.f);
            float a1 = atomicAdd(&acc[1], 0.f);
            float a2 = atomicAdd(&acc[2], 0.f);
            float a3 = atomicAdd(&acc[3], 0.f);
            float a4 = atomicAdd(&acc[4], 0.f);
            float a5 = atomicAdd(&acc[5], 0.f);
            out[0] = a0 + 0.5f * a1 + 20.f * a2 + a3 + a4 + a5;
        }
    }
}

extern "C" void kernel_launch(void* const* d_in, const int* in_sizes, int n_in,
                              void* d_out, int out_size, void* d_ws, size_t ws_size,
                              hipStream_t stream) {
    const float* pred_logits    = (const float*)d_in[0];
    const float* pred_normals   = (const float*)d_in[1];
    const float* pred_distances = (const float*)d_in[2];
    const float* gt_normals     = (const float*)d_in[3];
    const float* gt_distances   = (const float*)d_in[4];
    const int*   gt_masks       = (const int*)d_in[5];
    const float* points         = (const float*)d_in[6];
    const float* recon          = (const float*)d_in[7];
    const float* gt             = (const float*)d_in[8];
    // d_in[9] (gt_index) is unused by the reference.

    float* ws   = (float*)d_ws;
    float* cham = ws;
    float* ns   = ws + 1920;
    float* dd   = ws + 3840;
    float* cost = ws + 5760;
    float* cnt  = ws + 7680;
    float* acc  = ws + 7872;
    int*   cntr = (int*)(ws + 7888);
    float* rep  = ws + 7904;
    float* pmA1 = ws + 8192;
    float* pmA2 = ws + 90112;
    float* pmB1 = ws + 172032;
    float* pmB2 = ws + 253952;

    mega1_kernel<<<840, 256, 0, stream>>>(pred_normals, pred_distances, gt_normals,
                                          gt_distances, points, gt_masks, recon, gt,
                                          cham, ns, dd, cost, cnt, acc, rep,
                                          pmA1, pmA2, pmB1, pmB2);
    hungarian_kernel<<<Bn, 64, 0, stream>>>(cost, pred_logits, ns, dd, cham, cnt, acc);
    reduce_kernel<<<105, 256, 0, stream>>>(pmA1, pmA2, pmB1, pmB2, rep, acc, cntr,
                                           (float*)d_out);
}